// Round 4
// baseline (563.708 us; speedup 1.0000x reference)
//
#include <hip/hip_runtime.h>

#define T_STEPS 1000
#define B_TOT   2048
#define I_IN    40
#define H_N     16
#define TC      25
#define NCHUNK  40
#define EPB     4
#define BLOCK   256
#define ELEM_LDS   (TC*48)          // 1200 floats: [t][pair][24-slot]
#define CHUNK_LDS  (EPB*ELEM_LDS)   // 4800 floats
#define NUNIT      (EPB*TC*10)      // 1000 float4 units per chunk
#define LOGITS_OFF 1
#define CORR_OFF  (1 + 2*B_TOT*T_STEPS)   // 4096001
#define TOTAL_OFF (CORR_OFF + 1)          // 4096002

typedef float v2f __attribute__((ext_vector_type(2)));

__global__ void snn_init(float* out) {
    out[0] = 0.0f;
    out[CORR_OFF] = 0.0f;
    out[TOTAL_OFF] = 1216512.0f;   // 594 flagged steps * 2048 batch
}

// packed 2xf32 FMA: d = a*b + c (IEEE fma per component, bit-exact vs fmaf)
__device__ __forceinline__ v2f pk_fma(v2f a, v2f b, v2f c) {
    v2f d;
    asm("v_pk_fma_f32 %0, %1, %2, %3" : "=v"(d) : "v"(a), "v"(b), "v"(c));
    return d;
}
// quad_perm DPP adds (old=src avoids zero-materialize mov)
__device__ __forceinline__ float dpp_add_xor1(float v) {
    int s = __float_as_int(v);
    return v + __int_as_float(__builtin_amdgcn_update_dpp(s, s, 0xB1, 0xF, 0xF, true));
}
__device__ __forceinline__ float dpp_add_xor2(float v) {
    int s = __float_as_int(v);
    return v + __int_as_float(__builtin_amdgcn_update_dpp(s, s, 0x4E, 0xF, 0xF, true));
}

__global__ __launch_bounds__(BLOCK) void snn_main(
    const float* __restrict__ x, const int* __restrict__ target,
    const float* __restrict__ W1, const float* __restrict__ tau_m,
    const float* __restrict__ tau_n, const float* __restrict__ mask,
    const float* __restrict__ W2, const float* __restrict__ b2,
    float* __restrict__ out)
{
    __shared__ float xbuf[2][CHUNK_LDS];

    const int tid  = threadIdx.x;
    const int g    = tid >> 6;        // wave = batch elem within block (0..3)
    const int lane = tid & 63;
    const int p    = lane & 1;        // residue pair: components {2p,2p+1}
    const int br   = (lane >> 1) & 1; // branch
    const int n    = lane >> 2;       // neuron 0..15 (all 16 in this wave)
    const int r    = n*2 + br;        // dendritic row
    const int b0   = blockIdx.x * EPB;
    const int b    = b0 + g;

    // packed weight pairs: wp[j] = {Wm[r][4j+2p], Wm[r][4j+2p+1]}
    v2f wp[10];
#pragma unroll
    for (int j = 0; j < 10; ++j) {
        const int i = 4*j + 2*p;
        wp[j].x = W1[r*I_IN + i]     * mask[r*I_IN + i];
        wp[j].y = W1[r*I_IN + i + 1] * mask[r*I_IN + i + 1];
    }

    const float alpha = 1.0f / (1.0f + __expf(-tau_m[n]));
    const float beta  = 1.0f / (1.0f + __expf(-tau_n[r]));
    const float b2v0  = b2[0];
    const float b2v1  = b2[1];

    float w20[H_N], w21[H_N];
#pragma unroll
    for (int nn = 0; nn < H_N; ++nn) {
        w20[nn] = W2[nn];
        w21[nn] = W2[H_N + nn];
    }

    // staging: unit u = float4 group (e, tf, f4); split components into pair slots
    int  goff[4], lbase[4], lf4[4];
    bool gv[4];
#pragma unroll
    for (int jj = 0; jj < 4; ++jj) {
        const int u = tid + BLOCK*jj;
        gv[jj] = (u < NUNIT);
        const int uc = gv[jj] ? u : 0;
        const int e = uc/250, rem = uc%250, tf = rem/10, f4 = rem%10;
        goff[jj]  = ((b0+e)*T_STEPS + tf)*I_IN + 4*f4;
        lbase[jj] = e*ELEM_LDS + tf*48;
        lf4[jj]   = 2*f4;
    }

    float4 pf[4];
#pragma unroll
    for (int jj = 0; jj < 4; ++jj)
        if (gv[jj]) pf[jj] = *(const float4*)(x + goff[jj]);

    float d_st = 0.0f, mem = 0.0f, spk = 0.0f;
    float acc_loss = 0.0f, acc_corr = 0.0f;

    for (int c = 0; c < NCHUNK; ++c) {
        const int t0 = c * TC;
        float* buf = xbuf[c & 1];
#pragma unroll
        for (int jj = 0; jj < 4; ++jj) {
            if (gv[jj]) {
                *(float2*)(buf + lbase[jj] + lf4[jj])      = make_float2(pf[jj].x, pf[jj].y);
                *(float2*)(buf + lbase[jj] + 24 + lf4[jj]) = make_float2(pf[jj].z, pf[jj].w);
            }
        }
        __syncthreads();
        if (c + 1 < NCHUNK) {
            const int tadd = (t0 + TC) * I_IN;
#pragma unroll
            for (int jj = 0; jj < 4; ++jj)
                if (gv[jj]) pf[jj] = *(const float4*)(x + tadd + goff[jj]);
        }

        unsigned hist = 0u;
        const float* xg = buf + g*ELEM_LDS + p*24;
#pragma unroll
        for (int tt = 0; tt < TC; ++tt) {
            const float4* xp = (const float4*)(xg + tt*48);
            const float4 q0 = xp[0], q1 = xp[1], q2 = xp[2], q3 = xp[3], q4 = xp[4];
            v2f acc; acc.x = 0.0f; acc.y = 0.0f;
            v2f xa;
            xa.x=q0.x; xa.y=q0.y; acc = pk_fma(wp[0], xa, acc);
            xa.x=q0.z; xa.y=q0.w; acc = pk_fma(wp[1], xa, acc);
            xa.x=q1.x; xa.y=q1.y; acc = pk_fma(wp[2], xa, acc);
            xa.x=q1.z; xa.y=q1.w; acc = pk_fma(wp[3], xa, acc);
            xa.x=q2.x; xa.y=q2.y; acc = pk_fma(wp[4], xa, acc);
            xa.x=q2.z; xa.y=q2.w; acc = pk_fma(wp[5], xa, acc);
            xa.x=q3.x; xa.y=q3.y; acc = pk_fma(wp[6], xa, acc);
            xa.x=q3.z; xa.y=q3.w; acc = pk_fma(wp[7], xa, acc);
            xa.x=q4.x; xa.y=q4.y; acc = pk_fma(wp[8], xa, acc);
            xa.x=q4.z; xa.y=q4.w; acc = pk_fma(wp[9], xa, acc);
            const float loc = acc.x + acc.y;          // (s0+s1) or (s2+s3), R1 order
            const float cur = dpp_add_xor1(loc);      // (s0+s1)+(s2+s3), commutative-exact
            d_st = fmaf(beta, d_st - cur, cur);
            const float l = dpp_add_xor2(d_st);       // branch sum
            mem = fmaf(alpha, (mem - spk) - l, l);
            const bool fired = mem > 1.0f;
            spk = fired ? 1.0f : 0.0f;
            hist = (hist << 1) | (fired ? 1u : 0u);   // bit (24-tt) = fired@tt
        }

        // in-wave transpose via readlane: neuron n's hist lives in lane 4n
        unsigned hh[H_N];
#pragma unroll
        for (int nn = 0; nn < H_N; ++nn)
            hh[nn] = (unsigned)__builtin_amdgcn_readlane((int)hist, nn*4);

        if (lane < TC) {
            const int t  = t0 + lane;
            const int sh = (TC - 1) - lane;
            float sL0 = b2v0, sL1 = b2v1;
#pragma unroll
            for (int nn = 0; nn < H_N; ++nn) {   // same fma order as R2/R3 logits
                const float f = (float)((hh[nn] >> sh) & 1u);
                sL0 = fmaf(f, w20[nn], sL0);
                sL1 = fmaf(f, w21[nn], sL1);
            }
            const int oidx = (b*T_STEPS + t)*2;
            out[LOGITS_OFF + oidx]     = sL0;
            out[LOGITS_OFF + oidx + 1] = sL1;
            const bool flag = (t > 10) && (((t - 10) % 15) > 5);
            if (flag) {
                const int tgt = target[b*T_STEPS + t];
                float mx  = fmaxf(sL0, sL1);
                float e0  = __expf(sL0 - mx), e1 = __expf(sL1 - mx);
                float inv = 1.0f / (e0 + e1);
                float p0  = e0*inv, p1 = e1*inv;
                float mm  = fmaxf(p0, p1);
                float lse = mm + __logf(__expf(p0 - mm) + __expf(p1 - mm));
                float qv  = ((tgt == 1) ? p1 : p0) - lse;
                acc_loss -= qv;
                const int pred = (p1 > p0) ? 1 : 0;
                acc_corr += (pred == tgt) ? 1.0f : 0.0f;
            }
        }
    }

    acc_loss *= (1.0f / (float)B_TOT);
#pragma unroll
    for (int mk = 1; mk < 32; mk <<= 1) {   // only lanes 0..24 hold data; reduce low 32
        acc_loss += __shfl_xor(acc_loss, mk, 64);
        acc_corr += __shfl_xor(acc_corr, mk, 64);
    }
    if (lane == 0) {
        atomicAdd(out, acc_loss);
        atomicAdd(out + CORR_OFF, acc_corr);
    }
}

extern "C" void kernel_launch(void* const* d_in, const int* in_sizes, int n_in,
                              void* d_out, int out_size, void* d_ws, size_t ws_size,
                              hipStream_t stream) {
    const float* x      = (const float*)d_in[0];
    const int*   target = (const int*)d_in[1];
    const float* W1     = (const float*)d_in[2];
    const float* tau_m  = (const float*)d_in[3];
    const float* tau_n  = (const float*)d_in[4];
    const float* mask   = (const float*)d_in[5];
    const float* W2     = (const float*)d_in[6];
    const float* b2     = (const float*)d_in[7];
    float* out = (float*)d_out;

    snn_init<<<1, 1, 0, stream>>>(out);
    snn_main<<<B_TOT/EPB, BLOCK, 0, stream>>>(x, target, W1, tau_m, tau_n, mask, W2, b2, out);
}